// Round 4
// baseline (434.327 us; speedup 1.0000x reference)
//
#include <hip/hip_runtime.h>

#define B_  256
#define T_  512
#define HH  128
#define CC  10
#define CH  9                  // float4 stride per 8-float4 chunk (8 data + 1 pad)
#define BUFQ (CH*8)            // 72 float4 per parity buffer
#define BUFF (BUFQ*4)          // 288 floats per parity buffer

__device__ __forceinline__ float fast_rcp(float v) {
#if __has_builtin(__builtin_amdgcn_rcpf)
    return __builtin_amdgcn_rcpf(v);
#else
    return 1.0f / v;
#endif
}

// tanh(z) = sign(z) * (1 - e) / (1 + e),  e = exp(-2|z|).  ~7 VALU, rel err ~1e-6.
// tanh is contractive, so per-step error does not compound beyond ~T*1e-6 abs.
__device__ __forceinline__ float fast_tanh(float z) {
    float az = fabsf(z);
    float e  = __expf(-2.0f * az);
    float t  = (1.0f - e) * fast_rcp(1.0f + e);
    return copysignf(t, z);
}

// One block per batch row, 512 threads (8 waves; ~200 VGPR -> 2 waves/SIMD, the
// VGPR-capacity optimum given 128 VGPR of resident weights per thread).
//   threads [0,256):  layer-1 at step t      (inputs: x_t, h1_{t-1})
//   threads [256,512): layer-2 at step t-1   (inputs: h1_{t-1}, h2_{t-2})
// Per half: lt = tid&255, g = lt>>3 (rows 4g..4g+3), ks = lt&7 (k-chunk of 32 floats).
// Concat input vector (K=256 floats = 64 float4 = 8 chunks) lives in LDS with
// padded chunk stride CH=9 float4: reads are 8 bank-quads x 8-lane broadcast
// (conflict-free); h-writes land on 32 distinct banks.
// One __syncthreads() per step. 513 iterations (layer-2 lags by 1).
__global__ __launch_bounds__(512, 2) void rnn2_fused(
    const float* __restrict__ x,
    const float* __restrict__ Wih0, const float* __restrict__ Whh0,
    const float* __restrict__ bih0, const float* __restrict__ bhh0,
    const float* __restrict__ Wih1, const float* __restrict__ Whh1,
    const float* __restrict__ bih1, const float* __restrict__ bhh1,
    const float* __restrict__ Wfc,  const float* __restrict__ bfc,
    float* __restrict__ out)
{
    const int  tid  = threadIdx.x;
    const int  b    = blockIdx.x;
    const bool lay1 = tid < 256;
    const int  lt   = tid & 255;
    const int  g    = lt >> 3;     // row group: rows 4g..4g+3
    const int  ks   = lt & 7;      // chunk index: concat float4s [8ks, 8ks+8)
    const int  r0   = ks & 3;      // row (4g+r0) this lane finalizes
    const bool wr   = ks < 4;      // writer lanes (one per row)

    // [layer buffer][parity][floats]; layer buf 0 = [x | h1], buf 1 = [h1 | h2]
    __shared__ __align__(16) float sh[2][2][BUFF];

    // ---- weights -> registers (one-time, L2-resident) ----
    // chunk ks<4 multiplies the input half (W_ih), ks>=4 the recurrent half (W_hh)
    const float4* Wi = reinterpret_cast<const float4*>(lay1 ? Wih0 : Wih1);
    const float4* Wh = reinterpret_cast<const float4*>(lay1 ? Whh0 : Whh1);
    const float4* Ws = wr ? Wi : Wh;
    float4 w[4][8];
#pragma unroll
    for (int r = 0; r < 4; ++r)
#pragma unroll
        for (int j = 0; j < 8; ++j)
            w[r][j] = Ws[(4*g + r)*32 + 8*r0 + j];

    const int   hf   = 4*g + r0;
    const float bias = lay1 ? (bih0[hf] + bhh0[hf]) : (bih1[hf] + bhh1[hf]);

    // ---- LDS pointers (all loop-invariant; parity selected at call sites) ----
    const int Lrd = lay1 ? 0 : 1;
    const float4* rbP[2] = {
        reinterpret_cast<const float4*>(&sh[Lrd][0][0]) + CH*ks,
        reinterpret_cast<const float4*>(&sh[Lrd][1][0]) + CH*ks };
    // scalar addr of float 'comp' of chunk c, slot j:  4*(CH*c + j) + comp
    const int aSelf  = 4*(CH*(4 + (g>>3)) + (g&7)) + ks;  // own buffer, h-half
    const int aCross = 4*(CH*(g>>3) + (g&7)) + ks;        // buf1, h1-half (layer-1 only)
    float* wSelfP[2]  = { &sh[Lrd][0][aSelf],  &sh[Lrd][1][aSelf] };
    float* wCrossP[2] = { &sh[1][0][aCross],   &sh[1][1][aCross] };
    float4* xsP[2] = {
        reinterpret_cast<float4*>(&sh[0][0][0]) + CH*(tid>>3) + (tid&7),
        reinterpret_cast<float4*>(&sh[0][1][0]) + CH*(tid>>3) + (tid&7) };

    // ---- init: zero all state, stage x_0, prefetch x_1/x_2 ----
    for (int i = tid; i < 2*2*BUFF; i += 512)
        (&sh[0][0][0])[i] = 0.0f;
    __syncthreads();
    const float4* xb = reinterpret_cast<const float4*>(x) + (size_t)b*T_*32;
    float4 xe{}, xo{};
    if (tid < 32) {
        *xsP[0] = xb[0*32 + tid];
        xe = xb[1*32 + tid];
        xo = xb[2*32 + tid];
    }
    __syncthreads();

    auto step = [&](int t, const float4* rp, float* wS, float* wC,
                    float4* xsd, bool l2w, float4& xreg) {
        // stage x_{t+1} (loaded 2 steps ago) into the parity-nxt buffer FIRST:
        // that buffer was fully drained before the previous barrier, so this is
        // race-free, and it issues the next HBM load ~2 steps before its use.
        if (tid < 32) {
            *xsd = xreg;
            xreg = xb[(size_t)min(t + 3, T_ - 1)*32 + tid];
        }

        float4 v[8];
#pragma unroll
        for (int j = 0; j < 8; ++j) v[j] = rp[j];

        float a0 = 0.f, a1 = 0.f, a2 = 0.f, a3 = 0.f;
#pragma unroll
        for (int j = 0; j < 8; ++j) {
            a0 = fmaf(v[j].x, w[0][j].x, a0); a1 = fmaf(v[j].x, w[1][j].x, a1);
            a2 = fmaf(v[j].x, w[2][j].x, a2); a3 = fmaf(v[j].x, w[3][j].x, a3);
            a0 = fmaf(v[j].y, w[0][j].y, a0); a1 = fmaf(v[j].y, w[1][j].y, a1);
            a2 = fmaf(v[j].y, w[2][j].y, a2); a3 = fmaf(v[j].y, w[3][j].y, a3);
            a0 = fmaf(v[j].z, w[0][j].z, a0); a1 = fmaf(v[j].z, w[1][j].z, a1);
            a2 = fmaf(v[j].z, w[2][j].z, a2); a3 = fmaf(v[j].z, w[3][j].z, a3);
            a0 = fmaf(v[j].w, w[0][j].w, a0); a1 = fmaf(v[j].w, w[1][j].w, a1);
            a2 = fmaf(v[j].w, w[2][j].w, a2); a3 = fmaf(v[j].w, w[3][j].w, a3);
        }
        // quad reduce (DPP): sum over ks bits 0,1
        a0 += __shfl_xor(a0, 1); a1 += __shfl_xor(a1, 1);
        a2 += __shfl_xor(a2, 1); a3 += __shfl_xor(a3, 1);
        a0 += __shfl_xor(a0, 2); a1 += __shfl_xor(a1, 2);
        a2 += __shfl_xor(a2, 2); a3 += __shfl_xor(a3, 2);
        // lane picks its row, then combines the two chunk-quads (ih-half + hh-half)
        float s = (r0 & 1) ? ((r0 & 2) ? a3 : a1) : ((r0 & 2) ? a2 : a0);
        s += __shfl_xor(s, 4);
        float th = fast_tanh(s + bias);

        if (wr) {
            if (lay1 || l2w) *wS = th;   // layer-2 skips its (garbage) write at t==0
            if (lay1)        *wC = th;   // h1 also feeds layer-2's input half
        }
        __syncthreads();
    };

    // t = 0 .. 512 (513 iters; layer-2 computes h2_{t-1})
    step(0, rbP[0], wSelfP[1], wCrossP[1], xsP[1], false, xe);
#pragma unroll 1
    for (int i = 0; i < 255; ++i) {
        step(2*i + 1, rbP[1], wSelfP[0], wCrossP[0], xsP[0], true, xo);
        step(2*i + 2, rbP[0], wSelfP[1], wCrossP[1], xsP[1], true, xe);
    }
    step(511, rbP[1], wSelfP[0], wCrossP[0], xsP[0], true, xo);
    step(512, rbP[0], wSelfP[1], wCrossP[1], xsP[1], true, xe);
    // h2_511 now in sh[1][1] h-half (chunks 4..7)

    // ---- classifier on last h2 ----
    if (tid < 4*CC) {
        const int c = tid >> 2, q = tid & 3;
        const float4* hv   = reinterpret_cast<const float4*>(&sh[1][1][0]);
        const float4* Wfc4 = reinterpret_cast<const float4*>(Wfc);
        float a0 = 0.f, a1 = 0.f, a2 = 0.f, a3 = 0.f;
#pragma unroll
        for (int jj = 0; jj < 8; ++jj) {
            float4 v  = hv[CH*(4 + q) + jj];
            float4 ww = Wfc4[c*32 + q*8 + jj];
            a0 = fmaf(v.x, ww.x, a0); a1 = fmaf(v.y, ww.y, a1);
            a2 = fmaf(v.z, ww.z, a2); a3 = fmaf(v.w, ww.w, a3);
        }
        float r = (a0 + a1) + (a2 + a3);
        r += __shfl_xor(r, 1);
        r += __shfl_xor(r, 2);
        if (q == 0) out[b*CC + c] = r + bfc[c];
    }
}

extern "C" void kernel_launch(void* const* d_in, const int* in_sizes, int n_in,
                              void* d_out, int out_size, void* d_ws, size_t ws_size,
                              hipStream_t stream) {
    (void)in_sizes; (void)n_in; (void)d_ws; (void)ws_size; (void)out_size;
    const float* x    = (const float*)d_in[0];
    const float* Wih0 = (const float*)d_in[1];
    const float* Whh0 = (const float*)d_in[2];
    const float* bih0 = (const float*)d_in[3];
    const float* bhh0 = (const float*)d_in[4];
    const float* Wih1 = (const float*)d_in[5];
    const float* Whh1 = (const float*)d_in[6];
    const float* bih1 = (const float*)d_in[7];
    const float* bhh1 = (const float*)d_in[8];
    const float* Wfc  = (const float*)d_in[9];
    const float* bfc  = (const float*)d_in[10];
    float* out = (float*)d_out;

    rnn2_fused<<<B_, 512, 0, stream>>>(x, Wih0, Whh0, bih0, bhh0,
                                       Wih1, Whh1, bih1, bhh1, Wfc, bfc, out);
}

// Round 6
// 363.385 us; speedup vs baseline: 1.1952x; 1.1952x over previous
//
#include <hip/hip_runtime.h>

#define B_  256
#define T_  512
#define HH  128
#define CC  10
#define CH  9                  // float4 stride per 8-float4 chunk (8 data + 1 pad)
#define BUFQ (CH*8)            // 72 float4 per parity buffer
#define BUFF (BUFQ*4)          // 288 floats per parity buffer

__device__ __forceinline__ float fast_rcp(float v) {
#if __has_builtin(__builtin_amdgcn_rcpf)
    return __builtin_amdgcn_rcpf(v);
#else
    return 1.0f / v;
#endif
}

// tanh(z) = sign(z) * (1 - e) / (1 + e),  e = exp(-2|z|).  ~7 VALU, rel err ~1e-6.
__device__ __forceinline__ float fast_tanh(float z) {
    float az = fabsf(z);
    float e  = __expf(-2.0f * az);
    float t  = (1.0f - e) * fast_rcp(1.0f + e);
    return copysignf(t, z);
}

// xor-by-1 / xor-by-2 within quads via DPP quad_perm: single VALU add each,
// instead of __shfl_xor's ds_bpermute (LDS-pipe, ~30cyc serial in the tail).
// quad_perm encoding: perm[0] | perm[1]<<2 | perm[2]<<4 | perm[3]<<6.
__device__ __forceinline__ float qadd_xor1(float v) {   // [1,0,3,2] = 0xB1
    int s = __builtin_amdgcn_update_dpp(0, __float_as_int(v), 0xB1, 0xF, 0xF, true);
    return v + __int_as_float(s);
}
__device__ __forceinline__ float qadd_xor2(float v) {   // [2,3,0,1] = 0x4E
    int s = __builtin_amdgcn_update_dpp(0, __float_as_int(v), 0x4E, 0xF, 0xF, true);
    return v + __int_as_float(s);
}

// One block per batch row, 512 threads (8 waves).
//   threads [0,256):  layer-1 at step t      (inputs: x_t, h1_{t-1})
//   threads [256,512): layer-2 at step t-1   (inputs: h1_{t-1}, h2_{t-2})
// Per half: lt = tid&255, g = lt>>3 (rows 4g..4g+3), ks = lt&7 (k-chunk of 32 floats).
// Concat input vector (K=256 floats = 64 float4 = 8 chunks) lives in LDS with
// padded chunk stride CH=9 float4: reads are 8 bank-quads x 8-lane broadcast
// (conflict-free); h-writes land on 32 distinct banks.
// One __syncthreads() per step. 513 iterations (layer-2 lags by 1).
//
// __launch_bounds__(512, 1): R4 measured VGPR_Count=92 with (512,2) -> the 128
// weight VGPRs were parked in AGPRs with v_accvgpr_read round-trips (~+128
// VALU/step, matching measured ~317 vs expected ~165 instr/step). Relaxing the
// waves-per-EU hint lets the backend use the full schedulability cap (256 regs
// for an 8-wave workgroup) with an arch-register partition large enough for the
// weights; occupancy unchanged (8 waves/CU).
__global__ __launch_bounds__(512, 1) void rnn2_fused(
    const float* __restrict__ x,
    const float* __restrict__ Wih0, const float* __restrict__ Whh0,
    const float* __restrict__ bih0, const float* __restrict__ bhh0,
    const float* __restrict__ Wih1, const float* __restrict__ Whh1,
    const float* __restrict__ bih1, const float* __restrict__ bhh1,
    const float* __restrict__ Wfc,  const float* __restrict__ bfc,
    float* __restrict__ out)
{
    const int  tid  = threadIdx.x;
    const int  b    = blockIdx.x;
    const bool lay1 = tid < 256;
    const int  lt   = tid & 255;
    const int  g    = lt >> 3;     // row group: rows 4g..4g+3
    const int  ks   = lt & 7;      // chunk index: concat float4s [8ks, 8ks+8)
    const int  r0   = ks & 3;      // row (4g+r0) this lane finalizes
    const bool wr   = ks < 4;      // writer lanes (one per row)

    // [layer buffer][parity][floats]; layer buf 0 = [x | h1], buf 1 = [h1 | h2]
    __shared__ __align__(16) float sh[2][2][BUFF];

    // ---- weights -> registers (one-time, L2-resident) ----
    // chunk ks<4 multiplies the input half (W_ih), ks>=4 the recurrent half (W_hh)
    const float4* Wi = reinterpret_cast<const float4*>(lay1 ? Wih0 : Wih1);
    const float4* Wh = reinterpret_cast<const float4*>(lay1 ? Whh0 : Whh1);
    const float4* Ws = wr ? Wi : Wh;
    float4 w[4][8];
#pragma unroll
    for (int r = 0; r < 4; ++r)
#pragma unroll
        for (int j = 0; j < 8; ++j)
            w[r][j] = Ws[(4*g + r)*32 + 8*r0 + j];

    const int   hf   = 4*g + r0;
    const float bias = lay1 ? (bih0[hf] + bhh0[hf]) : (bih1[hf] + bhh1[hf]);

    // ---- LDS pointers (all loop-invariant; parity selected at call sites) ----
    const int Lrd = lay1 ? 0 : 1;
    const float4* rbP[2] = {
        reinterpret_cast<const float4*>(&sh[Lrd][0][0]) + CH*ks,
        reinterpret_cast<const float4*>(&sh[Lrd][1][0]) + CH*ks };
    // scalar addr of float 'comp' of chunk c, slot j:  4*(CH*c + j) + comp
    const int aSelf  = 4*(CH*(4 + (g>>3)) + (g&7)) + ks;  // own buffer, h-half
    const int aCross = 4*(CH*(g>>3) + (g&7)) + ks;        // buf1, h1-half (layer-1 only)
    float* wSelfP[2]  = { &sh[Lrd][0][aSelf],  &sh[Lrd][1][aSelf] };
    float* wCrossP[2] = { &sh[1][0][aCross],   &sh[1][1][aCross] };
    float4* xsP[2] = {
        reinterpret_cast<float4*>(&sh[0][0][0]) + CH*(tid>>3) + (tid&7),
        reinterpret_cast<float4*>(&sh[0][1][0]) + CH*(tid>>3) + (tid&7) };

    // ---- init: zero all state, stage x_0, prefetch x_1/x_2 ----
    for (int i = tid; i < 2*2*BUFF; i += 512)
        (&sh[0][0][0])[i] = 0.0f;
    __syncthreads();
    const float4* xb = reinterpret_cast<const float4*>(x) + (size_t)b*T_*32;
    float4 xe{}, xo{};
    if (tid < 32) {
        *xsP[0] = xb[0*32 + tid];
        xe = xb[1*32 + tid];
        xo = xb[2*32 + tid];
    }
    __syncthreads();

    auto step = [&](int t, const float4* rp, float* wS, float* wC,
                    float4* xsd, bool l2w, float4& xreg) {
        // stage x_{t+1} (loaded 2 steps ago) into the parity-nxt buffer FIRST:
        // that buffer was fully drained before the previous barrier, so this is
        // race-free, and it issues the next HBM load ~2 steps before its use.
        if (tid < 32) {
            *xsd = xreg;
            xreg = xb[(size_t)min(t + 3, T_ - 1)*32 + tid];
        }

        float4 v[8];
#pragma unroll
        for (int j = 0; j < 8; ++j) v[j] = rp[j];

        float a0 = 0.f, a1 = 0.f, a2 = 0.f, a3 = 0.f;
#pragma unroll
        for (int j = 0; j < 8; ++j) {
            a0 = fmaf(v[j].x, w[0][j].x, a0); a1 = fmaf(v[j].x, w[1][j].x, a1);
            a2 = fmaf(v[j].x, w[2][j].x, a2); a3 = fmaf(v[j].x, w[3][j].x, a3);
            a0 = fmaf(v[j].y, w[0][j].y, a0); a1 = fmaf(v[j].y, w[1][j].y, a1);
            a2 = fmaf(v[j].y, w[2][j].y, a2); a3 = fmaf(v[j].y, w[3][j].y, a3);
            a0 = fmaf(v[j].z, w[0][j].z, a0); a1 = fmaf(v[j].z, w[1][j].z, a1);
            a2 = fmaf(v[j].z, w[2][j].z, a2); a3 = fmaf(v[j].z, w[3][j].z, a3);
            a0 = fmaf(v[j].w, w[0][j].w, a0); a1 = fmaf(v[j].w, w[1][j].w, a1);
            a2 = fmaf(v[j].w, w[2][j].w, a2); a3 = fmaf(v[j].w, w[3][j].w, a3);
        }
        // quad reduce over ks bits 0,1 — DPP quad_perm adds (VALU, not LDS pipe)
        a0 = qadd_xor1(a0); a1 = qadd_xor1(a1);
        a2 = qadd_xor1(a2); a3 = qadd_xor1(a3);
        a0 = qadd_xor2(a0); a1 = qadd_xor2(a1);
        a2 = qadd_xor2(a2); a3 = qadd_xor2(a3);
        // lane picks its row, then combines the two chunk-quads (ih-half + hh-half)
        float s = (r0 & 1) ? ((r0 & 2) ? a3 : a1) : ((r0 & 2) ? a2 : a0);
        s += __shfl_xor(s, 4);
        float th = fast_tanh(s + bias);

        if (wr) {
            if (lay1 || l2w) *wS = th;   // layer-2 skips its (garbage) write at t==0
            if (lay1)        *wC = th;   // h1 also feeds layer-2's input half
        }
        __syncthreads();
    };

    // t = 0 .. 512 (513 iters; layer-2 computes h2_{t-1})
    step(0, rbP[0], wSelfP[1], wCrossP[1], xsP[1], false, xe);
#pragma unroll 1
    for (int i = 0; i < 255; ++i) {
        step(2*i + 1, rbP[1], wSelfP[0], wCrossP[0], xsP[0], true, xo);
        step(2*i + 2, rbP[0], wSelfP[1], wCrossP[1], xsP[1], true, xe);
    }
    step(511, rbP[1], wSelfP[0], wCrossP[0], xsP[0], true, xo);
    step(512, rbP[0], wSelfP[1], wCrossP[1], xsP[1], true, xe);
    // h2_511 now in sh[1][1] h-half (chunks 4..7)

    // ---- classifier on last h2 ----
    if (tid < 4*CC) {
        const int c = tid >> 2, q = tid & 3;
        const float4* hv   = reinterpret_cast<const float4*>(&sh[1][1][0]);
        const float4* Wfc4 = reinterpret_cast<const float4*>(Wfc);
        float a0 = 0.f, a1 = 0.f, a2 = 0.f, a3 = 0.f;
#pragma unroll
        for (int jj = 0; jj < 8; ++jj) {
            float4 v  = hv[CH*(4 + q) + jj];
            float4 ww = Wfc4[c*32 + q*8 + jj];
            a0 = fmaf(v.x, ww.x, a0); a1 = fmaf(v.y, ww.y, a1);
            a2 = fmaf(v.z, ww.z, a2); a3 = fmaf(v.w, ww.w, a3);
        }
        float r = (a0 + a1) + (a2 + a3);
        r += __shfl_xor(r, 1);
        r += __shfl_xor(r, 2);
        if (q == 0) out[b*CC + c] = r + bfc[c];
    }
}

extern "C" void kernel_launch(void* const* d_in, const int* in_sizes, int n_in,
                              void* d_out, int out_size, void* d_ws, size_t ws_size,
                              hipStream_t stream) {
    (void)in_sizes; (void)n_in; (void)d_ws; (void)ws_size; (void)out_size;
    const float* x    = (const float*)d_in[0];
    const float* Wih0 = (const float*)d_in[1];
    const float* Whh0 = (const float*)d_in[2];
    const float* bih0 = (const float*)d_in[3];
    const float* bhh0 = (const float*)d_in[4];
    const float* Wih1 = (const float*)d_in[5];
    const float* Whh1 = (const float*)d_in[6];
    const float* bih1 = (const float*)d_in[7];
    const float* bhh1 = (const float*)d_in[8];
    const float* Wfc  = (const float*)d_in[9];
    const float* bfc  = (const float*)d_in[10];
    float* out = (float*)d_out;

    rnn2_fused<<<B_, 512, 0, stream>>>(x, Wih0, Whh0, bih0, bhh0,
                                       Wih1, Whh1, bih1, bhh1, Wfc, bfc, out);
}

// Round 8
// 351.041 us; speedup vs baseline: 1.2373x; 1.0352x over previous
//
#include <hip/hip_runtime.h>

#define B_  256
#define T_  512
#define HH  128
#define CC  10
#define CH  9                  // float4 stride per 8-float4 chunk (8 data + 1 pad)
#define BUFQ (CH*8)            // 72 float4 per parity buffer
#define BUFF (BUFQ*4)          // 288 floats per parity buffer

__device__ __forceinline__ float fast_rcp(float v) {
#if __has_builtin(__builtin_amdgcn_rcpf)
    return __builtin_amdgcn_rcpf(v);
#else
    return 1.0f / v;
#endif
}

// tanh(z) = sign(z) * (1 - e) / (1 + e),  e = exp(-2|z|).  ~7 VALU, rel err ~1e-6.
__device__ __forceinline__ float fast_tanh(float z) {
    float az = fabsf(z);
    float e  = __expf(-2.0f * az);
    float t  = (1.0f - e) * fast_rcp(1.0f + e);
    return copysignf(t, z);
}

// xor-by-1 / xor-by-2 within quads via DPP quad_perm: single VALU add each,
// instead of __shfl_xor's ds_bpermute (LDS-pipe, ~30cyc serial in the tail).
// (R6 A/B: this + issue-efficiency gain took 388us -> 308us, VALUBusy 70->93%.)
__device__ __forceinline__ float qadd_xor1(float v) {   // [1,0,3,2] = 0xB1
    int s = __builtin_amdgcn_update_dpp(0, __float_as_int(v), 0xB1, 0xF, 0xF, true);
    return v + __int_as_float(s);
}
__device__ __forceinline__ float qadd_xor2(float v) {   // [2,3,0,1] = 0x4E
    int s = __builtin_amdgcn_update_dpp(0, __float_as_int(v), 0x4E, 0xF, 0xF, true);
    return v + __int_as_float(s);
}

// One block per batch row, 512 threads (8 waves = 2 waves/EU).
//   threads [0,256):  layer-1 at step t      (inputs: x_t, h1_{t-1})
//   threads [256,512): layer-2 at step t-1   (inputs: h1_{t-1}, h2_{t-2})
// Per half: lt = tid&255, g = lt>>3 (rows 4g..4g+3), ks = lt&7 (k-chunk of 32 floats).
// Concat input vector (K=256 floats = 8 chunks) in LDS, padded chunk stride CH=9
// float4 (bank-conflict-free broadcast reads). One __syncthreads() per step.
//
// amdgpu_waves_per_eu(2,2): R4/R6 both measured VGPR_Count=92 regardless of
// __launch_bounds__ second arg — HIP's minwaves is only a FLOOR; the allocator
// targeted ~5 waves/EU of arch regs (512/92) for occupancy we can never reach
// (1 block/CU = 2 waves/EU), parking the 128 weight regs in AGPRs and paying
// ~1 v_accvgpr_read per FMA (~128 extra VALU/step; measured ~290-335 vs ~155
// intended). Pinning min=max=2 sets the unified budget to 256 regs/wave so the
// ~190-reg pressure fits in arch VGPRs. Occupancy is unchanged by construction.
__global__ __launch_bounds__(512)
__attribute__((amdgpu_waves_per_eu(2, 2)))
void rnn2_fused(
    const float* __restrict__ x,
    const float* __restrict__ Wih0, const float* __restrict__ Whh0,
    const float* __restrict__ bih0, const float* __restrict__ bhh0,
    const float* __restrict__ Wih1, const float* __restrict__ Whh1,
    const float* __restrict__ bih1, const float* __restrict__ bhh1,
    const float* __restrict__ Wfc,  const float* __restrict__ bfc,
    float* __restrict__ out)
{
    const int  tid  = threadIdx.x;
    const int  b    = blockIdx.x;
    const bool lay1 = tid < 256;
    const int  lt   = tid & 255;
    const int  g    = lt >> 3;     // row group: rows 4g..4g+3
    const int  ks   = lt & 7;      // chunk index: concat float4s [8ks, 8ks+8)
    const int  r0   = ks & 3;      // row (4g+r0) this lane finalizes
    const bool wr   = ks < 4;      // writer lanes (one per row)

    // [layer buffer][parity][floats]; layer buf 0 = [x | h1], buf 1 = [h1 | h2]
    __shared__ __align__(16) float sh[2][2][BUFF];

    // ---- weights -> registers (one-time, L2-resident) ----
    // chunk ks<4 multiplies the input half (W_ih), ks>=4 the recurrent half (W_hh)
    const float4* Wi = reinterpret_cast<const float4*>(lay1 ? Wih0 : Wih1);
    const float4* Wh = reinterpret_cast<const float4*>(lay1 ? Whh0 : Whh1);
    const float4* Ws = wr ? Wi : Wh;
    float4 w[4][8];
#pragma unroll
    for (int r = 0; r < 4; ++r)
#pragma unroll
        for (int j = 0; j < 8; ++j)
            w[r][j] = Ws[(4*g + r)*32 + 8*r0 + j];

    const int   hf   = 4*g + r0;
    const float bias = lay1 ? (bih0[hf] + bhh0[hf]) : (bih1[hf] + bhh1[hf]);

    // ---- LDS pointers (all loop-invariant; parity selected at call sites) ----
    const int Lrd = lay1 ? 0 : 1;
    const float4* rbP[2] = {
        reinterpret_cast<const float4*>(&sh[Lrd][0][0]) + CH*ks,
        reinterpret_cast<const float4*>(&sh[Lrd][1][0]) + CH*ks };
    // scalar addr of float 'comp' of chunk c, slot j:  4*(CH*c + j) + comp
    const int aSelf  = 4*(CH*(4 + (g>>3)) + (g&7)) + ks;  // own buffer, h-half
    const int aCross = 4*(CH*(g>>3) + (g&7)) + ks;        // buf1, h1-half (layer-1 only)
    float* wSelfP[2]  = { &sh[Lrd][0][aSelf],  &sh[Lrd][1][aSelf] };
    float* wCrossP[2] = { &sh[1][0][aCross],   &sh[1][1][aCross] };
    float4* xsP[2] = {
        reinterpret_cast<float4*>(&sh[0][0][0]) + CH*(tid>>3) + (tid&7),
        reinterpret_cast<float4*>(&sh[0][1][0]) + CH*(tid>>3) + (tid&7) };

    // ---- init: zero all state, stage x_0, prefetch x_1/x_2 ----
    for (int i = tid; i < 2*2*BUFF; i += 512)
        (&sh[0][0][0])[i] = 0.0f;
    __syncthreads();
    const float4* xb = reinterpret_cast<const float4*>(x) + (size_t)b*T_*32;
    float4 xe{}, xo{};
    if (tid < 32) {
        *xsP[0] = xb[0*32 + tid];
        xe = xb[1*32 + tid];
        xo = xb[2*32 + tid];
    }
    __syncthreads();

    auto step = [&](int t, const float4* rp, float* wS, float* wC,
                    float4* xsd, bool l2w, float4& xreg) {
        // stage x_{t+1} (loaded 2 steps ago) into the parity-nxt buffer FIRST:
        // that buffer was fully drained before the previous barrier, so this is
        // race-free, and it issues the next HBM load ~2 steps before its use.
        if (tid < 32) {
            *xsd = xreg;
            xreg = xb[(size_t)min(t + 3, T_ - 1)*32 + tid];
        }

        float4 v[8];
#pragma unroll
        for (int j = 0; j < 8; ++j) v[j] = rp[j];

        float a0 = 0.f, a1 = 0.f, a2 = 0.f, a3 = 0.f;
#pragma unroll
        for (int j = 0; j < 8; ++j) {
            a0 = fmaf(v[j].x, w[0][j].x, a0); a1 = fmaf(v[j].x, w[1][j].x, a1);
            a2 = fmaf(v[j].x, w[2][j].x, a2); a3 = fmaf(v[j].x, w[3][j].x, a3);
            a0 = fmaf(v[j].y, w[0][j].y, a0); a1 = fmaf(v[j].y, w[1][j].y, a1);
            a2 = fmaf(v[j].y, w[2][j].y, a2); a3 = fmaf(v[j].y, w[3][j].y, a3);
            a0 = fmaf(v[j].z, w[0][j].z, a0); a1 = fmaf(v[j].z, w[1][j].z, a1);
            a2 = fmaf(v[j].z, w[2][j].z, a2); a3 = fmaf(v[j].z, w[3][j].z, a3);
            a0 = fmaf(v[j].w, w[0][j].w, a0); a1 = fmaf(v[j].w, w[1][j].w, a1);
            a2 = fmaf(v[j].w, w[2][j].w, a2); a3 = fmaf(v[j].w, w[3][j].w, a3);
        }
        // quad reduce over ks bits 0,1 — DPP quad_perm adds (VALU, not LDS pipe)
        a0 = qadd_xor1(a0); a1 = qadd_xor1(a1);
        a2 = qadd_xor1(a2); a3 = qadd_xor1(a3);
        a0 = qadd_xor2(a0); a1 = qadd_xor2(a1);
        a2 = qadd_xor2(a2); a3 = qadd_xor2(a3);
        // lane picks its row, then combines the two chunk-quads (ih-half + hh-half)
        float s = (r0 & 1) ? ((r0 & 2) ? a3 : a1) : ((r0 & 2) ? a2 : a0);
        s += __shfl_xor(s, 4);
        float th = fast_tanh(s + bias);

        if (wr) {
            if (lay1 || l2w) *wS = th;   // layer-2 skips its (garbage) write at t==0
            if (lay1)        *wC = th;   // h1 also feeds layer-2's input half
        }
        __syncthreads();
    };

    // t = 0 .. 512 (513 iters; layer-2 computes h2_{t-1})
    step(0, rbP[0], wSelfP[1], wCrossP[1], xsP[1], false, xe);
#pragma unroll 1
    for (int i = 0; i < 255; ++i) {
        step(2*i + 1, rbP[1], wSelfP[0], wCrossP[0], xsP[0], true, xo);
        step(2*i + 2, rbP[0], wSelfP[1], wCrossP[1], xsP[1], true, xe);
    }
    step(511, rbP[1], wSelfP[0], wCrossP[0], xsP[0], true, xo);
    step(512, rbP[0], wSelfP[1], wCrossP[1], xsP[1], true, xe);
    // h2_511 now in sh[1][1] h-half (chunks 4..7)

    // ---- classifier on last h2 ----
    if (tid < 4*CC) {
        const int c = tid >> 2, q = tid & 3;
        const float4* hv   = reinterpret_cast<const float4*>(&sh[1][1][0]);
        const float4* Wfc4 = reinterpret_cast<const float4*>(Wfc);
        float a0 = 0.f, a1 = 0.f, a2 = 0.f, a3 = 0.f;
#pragma unroll
        for (int jj = 0; jj < 8; ++jj) {
            float4 v  = hv[CH*(4 + q) + jj];
            float4 ww = Wfc4[c*32 + q*8 + jj];
            a0 = fmaf(v.x, ww.x, a0); a1 = fmaf(v.y, ww.y, a1);
            a2 = fmaf(v.z, ww.z, a2); a3 = fmaf(v.w, ww.w, a3);
        }
        float r = (a0 + a1) + (a2 + a3);
        r += __shfl_xor(r, 1);
        r += __shfl_xor(r, 2);
        if (q == 0) out[b*CC + c] = r + bfc[c];
    }
}

extern "C" void kernel_launch(void* const* d_in, const int* in_sizes, int n_in,
                              void* d_out, int out_size, void* d_ws, size_t ws_size,
                              hipStream_t stream) {
    (void)in_sizes; (void)n_in; (void)d_ws; (void)ws_size; (void)out_size;
    const float* x    = (const float*)d_in[0];
    const float* Wih0 = (const float*)d_in[1];
    const float* Whh0 = (const float*)d_in[2];
    const float* bih0 = (const float*)d_in[3];
    const float* bhh0 = (const float*)d_in[4];
    const float* Wih1 = (const float*)d_in[5];
    const float* Whh1 = (const float*)d_in[6];
    const float* bih1 = (const float*)d_in[7];
    const float* bhh1 = (const float*)d_in[8];
    const float* Wfc  = (const float*)d_in[9];
    const float* bfc  = (const float*)d_in[10];
    float* out = (float*)d_out;

    rnn2_fused<<<B_, 512, 0, stream>>>(x, Wih0, Whh0, bih0, bhh0,
                                       Wih1, Whh1, bih1, bhh1, Wfc, bfc, out);
}